// Round 6
// baseline (1120.634 us; speedup 1.0000x reference)
//
#include <hip/hip_runtime.h>

#define N_USERS 100000
#define N_ITEMS 50000
#define N_NODES 150000
#define DIM     32
#define N_EDGES 2400000
#define K_STEPS 10

#define SCAN_CHUNK 1024
#define NB_SCAN ((N_NODES + SCAN_CHUNK - 1) / SCAN_CHUNK)   // 147 blocks
#define WDEQ 3.814697265625e-06f   // 2^-18

typedef float v2f __attribute__((ext_vector_type(2)));

// ---------------- helpers: bf16 / fp8 ----------------
__device__ __forceinline__ float bflo(unsigned u) { return __uint_as_float(u << 16); }
__device__ __forceinline__ float bfhi(unsigned u) { return __uint_as_float(u & 0xffff0000u); }
__device__ __forceinline__ unsigned packbf(float a, float b) {   // RNE pack
    unsigned ua = __float_as_uint(a), ub = __float_as_uint(b);
    ua += 0x7fffu + ((ua >> 16) & 1u);
    ub += 0x7fffu + ((ub >> 16) & 1u);
    return (ua >> 16) | (ub & 0xffff0000u);
}
__device__ __forceinline__ unsigned pack_fp8x4(float a, float b, float c, float d) {
    unsigned r = 0;
    r = __builtin_amdgcn_cvt_pk_fp8_f32(a, b, r, false);   // bytes 0,1
    r = __builtin_amdgcn_cvt_pk_fp8_f32(c, d, r, true);    // bytes 2,3
    return r;
}
// per-edge accumulate: weight from CSR entry e, fp8x4 row dword r
#define EDGE_FMA(e, r)                                            \
    { float _w = (float)((e) & 0x3fffu) * WDEQ;                   \
      v2f _lo = __builtin_amdgcn_cvt_pk_f32_fp8((r), false);      \
      v2f _hi = __builtin_amdgcn_cvt_pk_f32_fp8((r), true);       \
      a0 = fmaf(_w, _lo[0], a0); a1 = fmaf(_w, _lo[1], a1);       \
      a2 = fmaf(_w, _hi[0], a2); a3 = fmaf(_w, _hi[1], a3); }

// ---------------- norm reduction: max over rows of sum(x^2) ----------------
__global__ void norm_kernel(const float* __restrict__ xu, const float* __restrict__ xi,
                            unsigned int* __restrict__ norm_bits) {
    int gid = blockIdx.x * blockDim.x + threadIdx.x;
    int row = gid >> 3;
    int q   = gid & 7;
    float s = 0.0f;
    if (row < N_NODES) {
        const float* x = (row < N_USERS) ? (xu + (size_t)row * DIM)
                                         : (xi + (size_t)(row - N_USERS) * DIM);
        float4 v = *(const float4*)(x + q * 4);
        s = v.x * v.x + v.y * v.y + v.z * v.z + v.w * v.w;
    }
    s += __shfl_xor(s, 1);
    s += __shfl_xor(s, 2);
    s += __shfl_xor(s, 4);
    s = fmaxf(s, __shfl_xor(s, 8));
    s = fmaxf(s, __shfl_xor(s, 16));
    s = fmaxf(s, __shfl_xor(s, 32));
    __shared__ float smax[4];
    int wave = threadIdx.x >> 6;
    if ((threadIdx.x & 63) == 0) smax[wave] = s;
    __syncthreads();
    if (threadIdx.x == 0) {
        float m = fmaxf(fmaxf(smax[0], smax[1]), fmaxf(smax[2], smax[3]));
        atomicMax(norm_bits, __float_as_uint(m));   // non-neg: uint order == float order
    }
}

// --------------------------- degree histogram ------------------------------
__global__ void hist_kernel(const int* __restrict__ ed, int* __restrict__ deg) {
    int e = blockIdx.x * blockDim.x + threadIdx.x;
    if (e >= N_EDGES) return;
    atomicAdd(&deg[ed[e]], 1);
}

// ----------------- degree-bucket counts (64 buckets) -----------------------
__global__ void degcnt_kernel(const int* __restrict__ deg, int* __restrict__ cnt) {
    __shared__ int lc[64];
    if (threadIdx.x < 64) lc[threadIdx.x] = 0;
    __syncthreads();
    int d = blockIdx.x * blockDim.x + threadIdx.x;
    if (d < N_NODES) {
        int dg = deg[d];
        atomicAdd(&lc[dg > 63 ? 63 : dg], 1);
    }
    __syncthreads();
    if (threadIdx.x < 64 && lc[threadIdx.x]) atomicAdd(&cnt[threadIdx.x], lc[threadIdx.x]);
}

// ------------- exclusive scan of the 64 bucket counts (1 wave) -------------
__global__ void scan_cnt_kernel(int* __restrict__ cnt) {
    int tid = threadIdx.x;          // 64 threads = 1 wave
    int v = cnt[tid];
    int inc = v;
    for (int off = 1; off < 64; off <<= 1) {
        int t = __shfl_up(inc, off);
        if (tid >= off) inc += t;
    }
    cnt[tid] = inc - v;             // exclusive offset; ticket advances it
}

// --- ticket: degree-sorted permutation. perm[pos]=node, pindex[node]=pos ---
__global__ void ticket_kernel(const int* __restrict__ deg, int* __restrict__ cnt,
                              int* __restrict__ perm, int* __restrict__ pindex,
                              int* __restrict__ pdeg, float* __restrict__ alphap,
                              const float* __restrict__ alpha_logit) {
    __shared__ int lcnt[64];
    __shared__ int lbase[64];
    int tid = threadIdx.x;
    if (tid < 64) lcnt[tid] = 0;
    __syncthreads();
    int d = blockIdx.x * blockDim.x + tid;
    int b = 0, rank = 0, dg = 0;
    if (d < N_NODES) {
        dg = deg[d];
        b = dg > 63 ? 63 : dg;
        rank = atomicAdd(&lcnt[b], 1);
    }
    __syncthreads();
    if (tid < 64 && lcnt[tid]) lbase[tid] = atomicAdd(&cnt[tid], lcnt[tid]);
    __syncthreads();
    if (d < N_NODES) {
        int pos = lbase[b] + rank;
        perm[pos] = d;
        pindex[d] = pos;
        pdeg[pos] = dg;
        alphap[pos] = 1.0f / (1.0f + __expf(-alpha_logit[d]));
    }
}

// ------------- per-block exclusive scan over pdeg (1024/block) -------------
__global__ void scan_block_kernel(const int* __restrict__ pdeg, int* __restrict__ excl,
                                  int* __restrict__ blockSums) {
    int base = blockIdx.x * SCAN_CHUNK + threadIdx.x * 4;
    int v0 = 0, v1 = 0, v2 = 0, v3 = 0;
    if (base + 3 < N_NODES) {
        int4 t = *(const int4*)(pdeg + base);
        v0 = t.x; v1 = t.y; v2 = t.z; v3 = t.w;
    } else {
        if (base + 0 < N_NODES) v0 = pdeg[base + 0];
        if (base + 1 < N_NODES) v1 = pdeg[base + 1];
        if (base + 2 < N_NODES) v2 = pdeg[base + 2];
    }
    int s = v0 + v1 + v2 + v3;
    int lane = threadIdx.x & 63;
    int inc = s;
    for (int off = 1; off < 64; off <<= 1) {
        int t = __shfl_up(inc, off);
        if (lane >= off) inc += t;
    }
    __shared__ int wsum[4];
    int wave = threadIdx.x >> 6;
    if (lane == 63) wsum[wave] = inc;
    __syncthreads();
    int woff = 0;
    for (int w = 0; w < 4; ++w) if (w < wave) woff += wsum[w];
    int excl_thread = woff + inc - s;
    if (base + 0 < N_NODES) excl[base + 0] = excl_thread;
    if (base + 1 < N_NODES) excl[base + 1] = excl_thread + v0;
    if (base + 2 < N_NODES) excl[base + 2] = excl_thread + v0 + v1;
    if (base + 3 < N_NODES) excl[base + 3] = excl_thread + v0 + v1 + v2;
    if (threadIdx.x == 255) blockSums[blockIdx.x] = woff + inc;
}

__global__ void scan_sums_kernel(int* __restrict__ blockSums) {
    __shared__ int buf[256];
    int tid = threadIdx.x;
    int v = (tid < NB_SCAN) ? blockSums[tid] : 0;
    buf[tid] = v;
    __syncthreads();
    for (int off = 1; off < 256; off <<= 1) {
        int t = (tid >= off) ? buf[tid - off] : 0;
        __syncthreads();
        buf[tid] += t;
        __syncthreads();
    }
    if (tid < NB_SCAN) blockSums[tid] = buf[tid] - v;   // exclusive
}

// prow[i] += blockoffset; sentinel prow[N_NODES] = N_EDGES
__global__ void add_offsets_kernel(int* __restrict__ prow, const int* __restrict__ blockSums) {
    int i = blockIdx.x * blockDim.x + threadIdx.x;
    if (i == 0) prow[N_NODES] = N_EDGES;
    if (i >= N_NODES) return;
    prow[i] += blockSums[i >> 10];
}

// node_cursor[node] = permuted row start (for fill's ticketing)
__global__ void nodestart_kernel(const int* __restrict__ perm, const int* __restrict__ prow,
                                 int* __restrict__ node_cursor) {
    int i = blockIdx.x * blockDim.x + threadIdx.x;
    if (i >= N_NODES) return;
    node_cursor[perm[i]] = prow[i];
}

// --- init: h(d_out) = x/norm; permuted fp8 mirror h8p; bf16 st16p ----------
// 8 lanes per node; lane q owns floats [q*4, q*4+4).
__global__ void init_kernel(const float* __restrict__ xu, const float* __restrict__ xi,
                            const float* __restrict__ su, const float* __restrict__ si,
                            const unsigned int* __restrict__ norm_bits,
                            const int* __restrict__ pindex,
                            float* __restrict__ h, unsigned* __restrict__ h8p,
                            unsigned* __restrict__ st16p) {
    int gid = blockIdx.x * blockDim.x + threadIdx.x;
    int d = gid >> 3;
    int q = gid & 7;
    if (d >= N_NODES) return;
    float rn = rsqrtf(__uint_as_float(*norm_bits));
    int fbase = d * DIM + (q << 2);
    const float* x = (d < N_USERS) ? (xu + fbase) : (xi + fbase - N_USERS * DIM);
    const float* s = (d < N_USERS) ? (su + fbase) : (si + fbase - N_USERS * DIM);
    float4 v = *(const float4*)x;
    v.x *= rn; v.y *= rn; v.z *= rn; v.w *= rn;
    *(float4*)(h + fbase) = v;
    int i = pindex[d];
    h8p[(i << 3) + q] = pack_fp8x4(v.x, v.y, v.z, v.w);
    float4 sv = *(const float4*)s;
    uint2 sp;
    sp.x = packbf(sv.x * rn, sv.y * rn);
    sp.y = packbf(sv.z * rn, sv.w * rn);
    *(uint2*)(st16p + (i << 4) + (q << 1)) = sp;
}

// -- fill: CSR entry = (pindex[src] << 14) | q14 at permuted row position ---
__global__ void fill_kernel(const int* __restrict__ es, const int* __restrict__ ed,
                            const float* __restrict__ ew, const int* __restrict__ pindex,
                            int* __restrict__ node_cursor, unsigned* __restrict__ csr) {
    int e = blockIdx.x * blockDim.x + threadIdx.x;
    if (e >= N_EDGES) return;
    int d = ed[e];
    int pos = atomicAdd(&node_cursor[d], 1);
    unsigned q = (unsigned)(ew[e] * 262144.0f + 0.5f);   // w in [0,1/16): q < 16384
    if (q > 16383u) q = 16383u;
    csr[pos] = ((unsigned)pindex[es[e]] << 14) | q;
}

// ---- hop-1 gather, software-pipelined (CSR prefetch 8 ahead) --------------
// 8 lanes/node, 1 dword (4 fp8) per lane per edge.
__global__ void gather1_kernel(const unsigned* __restrict__ h8p,
                               unsigned* __restrict__ t8p,
                               const unsigned* __restrict__ csr,
                               const int* __restrict__ prow) {
    int gid = blockIdx.x * blockDim.x + threadIdx.x;
    int i = gid >> 3;
    int q = gid & 7;
    if (i >= N_NODES) return;
    int j   = prow[i];
    int end = prow[i + 1];
    float a0 = 0, a1 = 0, a2 = 0, a3 = 0;
    int n8 = (end - j) >> 3;
    if (n8 > 0) {
        unsigned c0 = __builtin_nontemporal_load(csr + j);
        unsigned c1 = __builtin_nontemporal_load(csr + j + 1);
        unsigned c2 = __builtin_nontemporal_load(csr + j + 2);
        unsigned c3 = __builtin_nontemporal_load(csr + j + 3);
        unsigned c4 = __builtin_nontemporal_load(csr + j + 4);
        unsigned c5 = __builtin_nontemporal_load(csr + j + 5);
        unsigned c6 = __builtin_nontemporal_load(csr + j + 6);
        unsigned c7 = __builtin_nontemporal_load(csr + j + 7);
        for (int b = 1; b < n8; ++b) {
            const unsigned* nb = csr + j + (b << 3);
            unsigned e0 = c0, e1 = c1, e2 = c2, e3 = c3;
            unsigned e4 = c4, e5 = c5, e6 = c6, e7 = c7;
            // row loads for current block (8 independent, in flight together)
            unsigned r0 = h8p[((e0 >> 14) << 3) + q];
            unsigned r1 = h8p[((e1 >> 14) << 3) + q];
            unsigned r2 = h8p[((e2 >> 14) << 3) + q];
            unsigned r3 = h8p[((e3 >> 14) << 3) + q];
            unsigned r4 = h8p[((e4 >> 14) << 3) + q];
            unsigned r5 = h8p[((e5 >> 14) << 3) + q];
            unsigned r6 = h8p[((e6 >> 14) << 3) + q];
            unsigned r7 = h8p[((e7 >> 14) << 3) + q];
            // prefetch next block's CSR (overlaps row-load latency)
            c0 = __builtin_nontemporal_load(nb);
            c1 = __builtin_nontemporal_load(nb + 1);
            c2 = __builtin_nontemporal_load(nb + 2);
            c3 = __builtin_nontemporal_load(nb + 3);
            c4 = __builtin_nontemporal_load(nb + 4);
            c5 = __builtin_nontemporal_load(nb + 5);
            c6 = __builtin_nontemporal_load(nb + 6);
            c7 = __builtin_nontemporal_load(nb + 7);
            EDGE_FMA(e0, r0); EDGE_FMA(e1, r1); EDGE_FMA(e2, r2); EDGE_FMA(e3, r3);
            EDGE_FMA(e4, r4); EDGE_FMA(e5, r5); EDGE_FMA(e6, r6); EDGE_FMA(e7, r7);
        }
        {   // final full block (already in c0..c7)
            unsigned r0 = h8p[((c0 >> 14) << 3) + q];
            unsigned r1 = h8p[((c1 >> 14) << 3) + q];
            unsigned r2 = h8p[((c2 >> 14) << 3) + q];
            unsigned r3 = h8p[((c3 >> 14) << 3) + q];
            unsigned r4 = h8p[((c4 >> 14) << 3) + q];
            unsigned r5 = h8p[((c5 >> 14) << 3) + q];
            unsigned r6 = h8p[((c6 >> 14) << 3) + q];
            unsigned r7 = h8p[((c7 >> 14) << 3) + q];
            EDGE_FMA(c0, r0); EDGE_FMA(c1, r1); EDGE_FMA(c2, r2); EDGE_FMA(c3, r3);
            EDGE_FMA(c4, r4); EDGE_FMA(c5, r5); EDGE_FMA(c6, r6); EDGE_FMA(c7, r7);
        }
        j += n8 << 3;
    }
    for (; j < end; ++j) {
        unsigned e0 = __builtin_nontemporal_load(csr + j);
        unsigned r0 = h8p[((e0 >> 14) << 3) + q];
        EDGE_FMA(e0, r0);
    }
    t8p[(i << 3) + q] = pack_fp8x4(a0, a1, a2, a3);
}

// ---- hop-2 gather + update, software-pipelined; h fp32 in d_out -----------
__global__ void gather2_update_kernel(const unsigned* __restrict__ t8p,
                                      float* __restrict__ h,
                                      unsigned* __restrict__ h8p,
                                      const unsigned* __restrict__ csr,
                                      const int* __restrict__ prow,
                                      const int* __restrict__ perm,
                                      const unsigned* __restrict__ st16p,
                                      const float* __restrict__ alphap,
                                      const float* __restrict__ dt) {
    int gid = blockIdx.x * blockDim.x + threadIdx.x;
    int i = gid >> 3;
    int q = gid & 7;
    if (i >= N_NODES) return;
    int j   = prow[i];
    int end = prow[i + 1];
    float a0 = 0, a1 = 0, a2 = 0, a3 = 0;
    int n8 = (end - j) >> 3;
    if (n8 > 0) {
        unsigned c0 = __builtin_nontemporal_load(csr + j);
        unsigned c1 = __builtin_nontemporal_load(csr + j + 1);
        unsigned c2 = __builtin_nontemporal_load(csr + j + 2);
        unsigned c3 = __builtin_nontemporal_load(csr + j + 3);
        unsigned c4 = __builtin_nontemporal_load(csr + j + 4);
        unsigned c5 = __builtin_nontemporal_load(csr + j + 5);
        unsigned c6 = __builtin_nontemporal_load(csr + j + 6);
        unsigned c7 = __builtin_nontemporal_load(csr + j + 7);
        for (int b = 1; b < n8; ++b) {
            const unsigned* nb = csr + j + (b << 3);
            unsigned e0 = c0, e1 = c1, e2 = c2, e3 = c3;
            unsigned e4 = c4, e5 = c5, e6 = c6, e7 = c7;
            unsigned r0 = t8p[((e0 >> 14) << 3) + q];
            unsigned r1 = t8p[((e1 >> 14) << 3) + q];
            unsigned r2 = t8p[((e2 >> 14) << 3) + q];
            unsigned r3 = t8p[((e3 >> 14) << 3) + q];
            unsigned r4 = t8p[((e4 >> 14) << 3) + q];
            unsigned r5 = t8p[((e5 >> 14) << 3) + q];
            unsigned r6 = t8p[((e6 >> 14) << 3) + q];
            unsigned r7 = t8p[((e7 >> 14) << 3) + q];
            c0 = __builtin_nontemporal_load(nb);
            c1 = __builtin_nontemporal_load(nb + 1);
            c2 = __builtin_nontemporal_load(nb + 2);
            c3 = __builtin_nontemporal_load(nb + 3);
            c4 = __builtin_nontemporal_load(nb + 4);
            c5 = __builtin_nontemporal_load(nb + 5);
            c6 = __builtin_nontemporal_load(nb + 6);
            c7 = __builtin_nontemporal_load(nb + 7);
            EDGE_FMA(e0, r0); EDGE_FMA(e1, r1); EDGE_FMA(e2, r2); EDGE_FMA(e3, r3);
            EDGE_FMA(e4, r4); EDGE_FMA(e5, r5); EDGE_FMA(e6, r6); EDGE_FMA(e7, r7);
        }
        {
            unsigned r0 = t8p[((c0 >> 14) << 3) + q];
            unsigned r1 = t8p[((c1 >> 14) << 3) + q];
            unsigned r2 = t8p[((c2 >> 14) << 3) + q];
            unsigned r3 = t8p[((c3 >> 14) << 3) + q];
            unsigned r4 = t8p[((c4 >> 14) << 3) + q];
            unsigned r5 = t8p[((c5 >> 14) << 3) + q];
            unsigned r6 = t8p[((c6 >> 14) << 3) + q];
            unsigned r7 = t8p[((c7 >> 14) << 3) + q];
            EDGE_FMA(c0, r0); EDGE_FMA(c1, r1); EDGE_FMA(c2, r2); EDGE_FMA(c3, r3);
            EDGE_FMA(c4, r4); EDGE_FMA(c5, r5); EDGE_FMA(c6, r6); EDGE_FMA(c7, r7);
        }
        j += n8 << 3;
    }
    for (; j < end; ++j) {
        unsigned e0 = __builtin_nontemporal_load(csr + j);
        unsigned r0 = t8p[((e0 >> 14) << 3) + q];
        EDGE_FMA(e0, r0);
    }
    float step = dt[0] * (1.0f / K_STEPS);
    float al = alphap[i];
    int d = perm[i];
    int fbase = d * DIM + (q << 2);
    float4 hv = *(const float4*)(h + fbase);
    uint2 sp = *(const uint2*)(st16p + (i << 4) + (q << 1));
    hv.x += step * (a0 - al * hv.x + bflo(sp.x));
    hv.y += step * (a1 - al * hv.y + bfhi(sp.x));
    hv.z += step * (a2 - al * hv.z + bflo(sp.y));
    hv.w += step * (a3 - al * hv.w + bfhi(sp.y));
    *(float4*)(h + fbase) = hv;
    h8p[(i << 3) + q] = pack_fp8x4(hv.x, hv.y, hv.z, hv.w);
}

extern "C" void kernel_launch(void* const* d_in, const int* in_sizes, int n_in,
                              void* d_out, int out_size, void* d_ws, size_t ws_size,
                              hipStream_t stream) {
    const float* xu          = (const float*)d_in[0];
    const float* xi          = (const float*)d_in[1];
    const float* su          = (const float*)d_in[2];
    const float* si          = (const float*)d_in[3];
    const float* ew          = (const float*)d_in[4];
    const float* alpha_logit = (const float*)d_in[5];
    const float* dt          = (const float*)d_in[6];
    const int*   es          = (const int*)d_in[7];
    const int*   ed          = (const int*)d_in[8];
    float* h = (float*)d_out;                     // fp32 h lives in d_out (node order)

    // ---- workspace layout (~34 MB) ----
    char* base = (char*)d_ws;
    unsigned int* norm_bits = (unsigned int*)base;              // 4 B
    int* cnt       = (int*)(base + 64);                         // 64 ints
    int* blockSums = (int*)(base + 512);                        // 256 ints
    const size_t SLOT = 640 * 1024;                             // 640 KB slots
    int*   deg         = (int*)(base + 4096 + 0 * SLOT);
    int*   perm        = (int*)(base + 4096 + 1 * SLOT);
    int*   pindex      = (int*)(base + 4096 + 2 * SLOT);
    int*   pdeg        = (int*)(base + 4096 + 3 * SLOT);
    int*   prow        = (int*)(base + 4096 + 4 * SLOT);        // N_NODES+1 entries
    int*   node_cursor = (int*)(base + 4096 + 5 * SLOT);
    float* alphap      = (float*)(base + 4096 + 6 * SLOT);
    unsigned* csr   = (unsigned*)(base + 5u * 1024 * 1024);     // 9.6 MB
    unsigned* t8p   = csr + N_EDGES;                            // 4.8 MB (fp8 rows)
    unsigned* h8p   = t8p + (size_t)N_NODES * 8;                // 4.8 MB (fp8 rows)
    unsigned* st16p = h8p + (size_t)N_NODES * 8;                // 9.6 MB (bf16 rows)

    hipMemsetAsync(norm_bits, 0, sizeof(unsigned int), stream);
    hipMemsetAsync(cnt, 0, 64 * sizeof(int), stream);
    hipMemsetAsync(deg, 0, (size_t)N_NODES * sizeof(int), stream);

    const int nodeb  = (N_NODES + 255) / 256;
    const int edgeb  = (N_EDGES + 255) / 256;
    const int node8b = (N_NODES * 8 + 255) / 256;

    norm_kernel<<<(N_NODES * 8 + 255) / 256, 256, 0, stream>>>(xu, xi, norm_bits);
    hist_kernel<<<edgeb, 256, 0, stream>>>(ed, deg);
    degcnt_kernel<<<nodeb, 256, 0, stream>>>(deg, cnt);
    scan_cnt_kernel<<<1, 64, 0, stream>>>(cnt);
    ticket_kernel<<<nodeb, 256, 0, stream>>>(deg, cnt, perm, pindex, pdeg, alphap, alpha_logit);
    scan_block_kernel<<<NB_SCAN, 256, 0, stream>>>(pdeg, prow, blockSums);
    scan_sums_kernel<<<1, 256, 0, stream>>>(blockSums);
    add_offsets_kernel<<<nodeb, 256, 0, stream>>>(prow, blockSums);
    nodestart_kernel<<<nodeb, 256, 0, stream>>>(perm, prow, node_cursor);
    init_kernel<<<node8b, 256, 0, stream>>>(xu, xi, su, si, norm_bits, pindex, h, h8p, st16p);
    fill_kernel<<<edgeb, 256, 0, stream>>>(es, ed, ew, pindex, node_cursor, csr);

    for (int k = 0; k < K_STEPS; ++k) {
        gather1_kernel<<<node8b, 256, 0, stream>>>(h8p, t8p, csr, prow);
        gather2_update_kernel<<<node8b, 256, 0, stream>>>(t8p, h, h8p, csr, prow,
                                                          perm, st16p, alphap, dt);
    }
}